// Round 3
// baseline (132.632 us; speedup 1.0000x reference)
//
#include <hip/hip_runtime.h>
#include <hip/hip_bf16.h>
#include <cstdint>
#include <cstddef>

#define BB 32
#define SS 4096
#define DD 256
#define UU 256

typedef __attribute__((ext_vector_type(8))) short short8;
typedef __attribute__((ext_vector_type(4))) float f32x4;

struct __align__(16) ui4 { unsigned int a, b, c, d; };

__device__ __forceinline__ unsigned short f2bf(float x) {
  union { float f; unsigned int u; } c; c.f = x;
  unsigned int r = c.u + 0x7FFFu + ((c.u >> 16) & 1u);
  return (unsigned short)(r >> 16);
}

// pack2(lo, hi) -> u32 [bf16(hi)<<16 | bf16(lo)], round-half-up
__device__ __forceinline__ unsigned int bfpack2(float lo, float hi) {
  union { float f; unsigned int u; } a, b;
  a.f = hi; b.f = lo;
  return __builtin_amdgcn_perm(a.u + 0x8000u, b.u + 0x8000u, 0x07060302u);
}

__device__ __forceinline__ short8 bfpack8(float4 f0, float4 f1) {
  union { unsigned int u[4]; short8 s; } r;
  r.u[0] = bfpack2(f0.x, f0.y);
  r.u[1] = bfpack2(f0.z, f0.w);
  r.u[2] = bfpack2(f1.x, f1.y);
  r.u[3] = bfpack2(f1.z, f1.w);
  return r.s;
}

// K1: posb[b][u] = position[b] @ W1[:,u] + b1[u] + b2[u]   (exact fp32)
__global__ void k_posproj(const float* __restrict__ pos, const float* __restrict__ W1,
                          const float* __restrict__ b1, const float* __restrict__ b2,
                          float* __restrict__ posb) {
  __shared__ float p[DD];
  int b = blockIdx.x, u = threadIdx.x;
  p[u] = pos[b * DD + u];
  __syncthreads();
  float acc = b1[u] + b2[u];
#pragma unroll 4
  for (int d = 0; d < DD; ++d) acc = fmaf(p[d], W1[(size_t)d * UU + u], acc);
  posb[b * UU + u] = acc;
}

// K1b: w2t[u][d] = bf16(W2[d][u])  (tiled transpose)
__global__ void k_w2t(const float* __restrict__ W2, unsigned short* __restrict__ w2t) {
  __shared__ unsigned short tile[16][17];
  int di = blockIdx.x * 16, ui = blockIdx.y * 16;
  int t = threadIdx.x;
  int r = t >> 4, c = t & 15;
  tile[c][r] = f2bf(W2[(size_t)(di + r) * UU + ui + c]);
  __syncthreads();
  w2t[(size_t)(ui + r) * DD + di + c] = tile[r][c];
}

// K2 (fused, LDS-free GEMM): per 64-row chunk:
//   score[s] = sum_u tanh(posb[u] + opt[s]@W2[:,u]) * V[u] + bv
//   m = max_s score, p_s = exp(score_s - m), l = sum p
//   part_ctx[d] = sum_s p_s * opt[s][d]   (fp32 re-read, L2/L3-hot)
__global__ __launch_bounds__(256) void k_score_ctx(
    const float* __restrict__ options, const unsigned short* __restrict__ w2t,
    const float* __restrict__ posb, const float* __restrict__ V,
    const float* __restrict__ bvp, float* __restrict__ scores,
    float* __restrict__ part, float2* __restrict__ ml) {
  __shared__ float posv_l[UU];
  __shared__ float vv_l[UU];
  __shared__ float red[64][2];
  __shared__ float pbuf[64];
  __shared__ float4 pr[256];

  const int tid = threadIdx.x;
  const int ch = blockIdx.x;
  const int b  = blockIdx.y;
  const int s0 = ch * 64;
  const int wid = tid >> 6, l = tid & 63;
  const int wr = wid >> 1, wc = wid & 1;
  const int il = l & 15, kg = l >> 4;

  posv_l[tid] = posb[b * UU + tid];
  vv_l[tid]   = V[tid];

  const float* optb = options + ((size_t)b * SS + s0) * DD;

  f32x4 acc[2][8];
#pragma unroll
  for (int mi = 0; mi < 2; ++mi)
#pragma unroll
    for (int ni = 0; ni < 8; ++ni) {
      f32x4 z = {0.f, 0.f, 0.f, 0.f};
      acc[mi][ni] = z;
    }

  // per-lane base pointers
  const float* aptr = optb + (size_t)(wr * 32 + il) * DD + kg * 8;        // + mi*16*DD + ko
  const unsigned short* bptr = w2t + (size_t)(wc * 128 + il) * DD + kg * 8; // + ni*16*DD + ko

#pragma unroll
  for (int kc0 = 0; kc0 < DD; kc0 += 64) {
#pragma unroll
    for (int kc = 0; kc < 2; ++kc) {
      const int ko = kc0 + kc * 32;
      short8 af[2];
#pragma unroll
      for (int mi = 0; mi < 2; ++mi) {
        const float* ap = aptr + (size_t)mi * 16 * DD + ko;
        float4 f0 = *(const float4*)(ap);
        float4 f1 = *(const float4*)(ap + 4);
        af[mi] = bfpack8(f0, f1);
      }
#pragma unroll
      for (int ni = 0; ni < 8; ++ni) {
        short8 bf = *(const short8*)(bptr + (size_t)ni * 16 * DD + ko);
        acc[0][ni] = __builtin_amdgcn_mfma_f32_16x16x32_bf16(af[0], bf, acc[0][ni], 0, 0, 0);
        acc[1][ni] = __builtin_amdgcn_mfma_f32_16x16x32_bf16(af[1], bf, acc[1][ni], 0, 0, 0);
      }
    }
  }

  __syncthreads();   // posv_l / vv_l visibility

  // epilogue: tanh(acc + posb) * V, reduce over u
  float part_r[2][4];
#pragma unroll
  for (int mi = 0; mi < 2; ++mi)
#pragma unroll
    for (int r = 0; r < 4; ++r) part_r[mi][r] = 0.f;

#pragma unroll
  for (int ni = 0; ni < 8; ++ni) {
    int u = wc * 128 + ni * 16 + il;
    float pv = posv_l[u], vv = vv_l[u];
#pragma unroll
    for (int mi = 0; mi < 2; ++mi)
#pragma unroll
      for (int r = 0; r < 4; ++r) {
        float x = acc[mi][ni][r] + pv;
        float t = 1.f - __fdividef(2.f, __expf(2.f * x) + 1.f);
        part_r[mi][r] = fmaf(t, vv, part_r[mi][r]);
      }
  }
#pragma unroll
  for (int mi = 0; mi < 2; ++mi)
#pragma unroll
    for (int r = 0; r < 4; ++r) {
      float p = part_r[mi][r];
      p += __shfl_xor(p, 1);
      p += __shfl_xor(p, 2);
      p += __shfl_xor(p, 4);
      p += __shfl_xor(p, 8);
      part_r[mi][r] = p;
    }
  if (il == 0) {
#pragma unroll
    for (int mi = 0; mi < 2; ++mi)
#pragma unroll
      for (int r = 0; r < 4; ++r)
        red[wr * 32 + mi * 16 + kg * 4 + r][wc] = part_r[mi][r];
  }
  __syncthreads();

  // local softmax stats over the 64 rows (wave 0)
  const float bvv = bvp[0];
  if (tid < 64) {
    float sv = red[tid][0] + red[tid][1] + bvv;
    scores[(size_t)b * SS + s0 + tid] = sv;
    float m = sv;
#pragma unroll
    for (int off = 32; off >= 1; off >>= 1) m = fmaxf(m, __shfl_xor(m, off));
    float p = __expf(sv - m);
    float ls = p;
#pragma unroll
    for (int off = 32; off >= 1; off >>= 1) ls += __shfl_xor(ls, off);
    pbuf[tid] = p;
    if (tid == 0) ml[b * 64 + ch] = make_float2(m, ls);
  }
  __syncthreads();

  // partial context: fp32 re-read of the tile (L2/L3-hot)
  {
    int rg = tid >> 6;
    int d4 = (tid & 63) << 2;
    float a0 = 0.f, a1 = 0.f, a2 = 0.f, a3 = 0.f;
#pragma unroll 4
    for (int i = 0; i < 16; ++i) {
      int s = i * 4 + rg;
      const float4 o = *(const float4*)(optb + (size_t)s * DD + d4);
      float w = pbuf[s];
      a0 = fmaf(w, o.x, a0); a1 = fmaf(w, o.y, a1);
      a2 = fmaf(w, o.z, a2); a3 = fmaf(w, o.w, a3);
    }
    pr[tid] = make_float4(a0, a1, a2, a3);
  }
  __syncthreads();
  if (tid < 64) {
    int d4 = tid << 2;
    float4 v0 = pr[tid], v1 = pr[64 + tid], v2 = pr[128 + tid], v3 = pr[192 + tid];
    float4 o;
    o.x = v0.x + v1.x + v2.x + v3.x;
    o.y = v0.y + v1.y + v2.y + v3.y;
    o.z = v0.z + v1.z + v2.z + v3.z;
    o.w = v0.w + v1.w + v2.w + v3.w;
    *(float4*)&part[(((size_t)b * 64 + ch) * DD) + d4] = o;
  }
}

// K3: per batch — combine 64 chunk partials, emit context + weights
__global__ __launch_bounds__(256) void k_final(
    const float* __restrict__ scores, const float* __restrict__ part,
    const float2* __restrict__ ml, float* __restrict__ ctx,
    float* __restrict__ wgt) {
  __shared__ float ms[64], lsh[64];
  int b = blockIdx.x, t = threadIdx.x;
  if (t < 64) { float2 v = ml[b * 64 + t]; ms[t] = v.x; lsh[t] = v.y; }
  __syncthreads();
  float gm = ms[0];
#pragma unroll
  for (int i = 1; i < 64; ++i) gm = fmaxf(gm, ms[i]);
  float gs = 0.f;
#pragma unroll
  for (int i = 0; i < 64; ++i) gs += lsh[i] * __expf(ms[i] - gm);
  float inv = 1.f / gs;
  // context: d = t
  float acc = 0.f;
#pragma unroll 4
  for (int i = 0; i < 64; ++i)
    acc += part[((size_t)b * 64 + i) * DD + t] * __expf(ms[i] - gm);
  ctx[b * DD + t] = acc * inv;
  // weights
  const float* sb = scores + (size_t)b * SS;
  float* wb = wgt + (size_t)b * SS;
#pragma unroll 4
  for (int i = 0; i < 16; ++i) {
    int s = i * 256 + t;
    wb[s] = __expf(sb[s] - gm) * inv;
  }
}

extern "C" void kernel_launch(void* const* d_in, const int* in_sizes, int n_in,
                              void* d_out, int out_size, void* d_ws, size_t ws_size,
                              hipStream_t stream) {
  const float* position = (const float*)d_in[0];
  const float* options  = (const float*)d_in[1];
  const float* W1 = (const float*)d_in[2];
  const float* b1 = (const float*)d_in[3];
  const float* W2 = (const float*)d_in[4];
  const float* b2 = (const float*)d_in[5];
  const float* V  = (const float*)d_in[6];
  const float* bv = (const float*)d_in[7];

  float* out = (float*)d_out;
  float* ctx_out = out;              // [32,256]
  float* wgt_out = out + BB * DD;    // [32,4096]

  char* ws = (char*)d_ws;
  float* posb         = (float*)ws;                          // 32 KB
  unsigned short* w2t = (unsigned short*)(ws + 32 * 1024);   // 128 KB
  float* scores       = (float*)(ws + 160 * 1024);           // 512 KB
  float* part         = (float*)(ws + 672 * 1024);           // 2 MB
  float2* ml          = (float2*)(ws + 672 * 1024 + 2 * 1024 * 1024); // 16 KB

  k_posproj<<<BB, 256, 0, stream>>>(position, W1, b1, b2, posb);
  k_w2t<<<dim3(16, 16), 256, 0, stream>>>(W2, w2t);
  k_score_ctx<<<dim3(SS / 64, BB), 256, 0, stream>>>(options, w2t, posb, V, bv,
                                                     scores, part, ml);
  k_final<<<BB, 256, 0, stream>>>(scores, part, ml, ctx_out, wgt_out);
}

// Round 4
// 81.069 us; speedup vs baseline: 1.6360x; 1.6360x over previous
//
#include <hip/hip_runtime.h>
#include <hip/hip_bf16.h>
#include <cstdint>
#include <cstddef>

#define BB 32
#define SS 4096
#define DD 256
#define UU 256
#define BM 128
#define NCH (SS / BM)   // 32 chunks per batch

typedef __attribute__((ext_vector_type(8))) short short8;
typedef __attribute__((ext_vector_type(4))) float f32x4;

__device__ __forceinline__ unsigned short f2bf(float x) {
  union { float f; unsigned int u; } c; c.f = x;
  unsigned int r = c.u + 0x7FFFu + ((c.u >> 16) & 1u);
  return (unsigned short)(r >> 16);
}

// pack2(lo, hi) -> u32 [bf16(hi)<<16 | bf16(lo)], round-half-up
__device__ __forceinline__ unsigned int bfpack2(float lo, float hi) {
  union { float f; unsigned int u; } a, b;
  a.f = hi; b.f = lo;
  return __builtin_amdgcn_perm(a.u + 0x8000u, b.u + 0x8000u, 0x07060302u);
}

__device__ __forceinline__ short8 bfpack8(float4 f0, float4 f1) {
  union { unsigned int u[4]; short8 s; } r;
  r.u[0] = bfpack2(f0.x, f0.y);
  r.u[1] = bfpack2(f0.z, f0.w);
  r.u[2] = bfpack2(f1.x, f1.y);
  r.u[3] = bfpack2(f1.z, f1.w);
  return r.s;
}

// K1: posb[b][u] = position[b] @ W1[:,u] + b1[u] + b2[u]   (exact fp32)
__global__ void k_posproj(const float* __restrict__ pos, const float* __restrict__ W1,
                          const float* __restrict__ b1, const float* __restrict__ b2,
                          float* __restrict__ posb) {
  __shared__ float p[DD];
  int b = blockIdx.x, u = threadIdx.x;
  p[u] = pos[b * DD + u];
  __syncthreads();
  float acc = b1[u] + b2[u];
#pragma unroll 4
  for (int d = 0; d < DD; ++d) acc = fmaf(p[d], W1[(size_t)d * UU + u], acc);
  posb[b * UU + u] = acc;
}

// K1b: w2t[u][d] = bf16(W2[d][u])  (tiled transpose)
__global__ void k_w2t(const float* __restrict__ W2, unsigned short* __restrict__ w2t) {
  __shared__ unsigned short tile[16][17];
  int di = blockIdx.x * 16, ui = blockIdx.y * 16;
  int t = threadIdx.x;
  int r = t >> 4, c = t & 15;
  tile[c][r] = f2bf(W2[(size_t)(di + r) * UU + ui + c]);
  __syncthreads();
  w2t[(size_t)(ui + r) * DD + di + c] = tile[r][c];
}

// K2 (fused): per 128-row chunk:
//   score[s] = sum_u tanh(posb[u] + opt[s]@W2[:,u]) * V[u] + bv
//   m,l local softmax stats; part_ctx[d] = sum_s exp(score-m) * opt[s][d]
// LDS: A tile [128][64k] bf16 swz (16 KB) + B tile [256u][64k] bf16 swz (32 KB).
// Swizzle: 16B-unit index k8 stored at slot k8 ^ (row&7).
__global__ __launch_bounds__(512, 4) void k_score_ctx(
    const float* __restrict__ options, const unsigned short* __restrict__ w2t,
    const float* __restrict__ posb, const float* __restrict__ V,
    const float* __restrict__ bvp, float* __restrict__ scores,
    float* __restrict__ part, float2* __restrict__ ml) {
  __shared__ __align__(16) unsigned char smem[49152];   // 48 KB
  unsigned char* aB = smem;            // A tile: 16384 B
  unsigned char* bB = smem + 16384;    // B tile: 32768 B
  // epilogue overlay (inside aB after GEMM):
  float (*red)[4] = (float (*)[4])smem;                 // [128][4]  @0     (2 KB)
  float* pbuf     = (float*)(smem + 2048);              // [128]            (0.5 KB)
  float* posvL    = (float*)(smem + 2560);              // [256]            (1 KB)
  float* vvL      = (float*)(smem + 3584);              // [256]            (1 KB)
  float4* pr      = (float4*)(smem + 8192);             // [512]            (8 KB)

  const int tid = threadIdx.x;
  const int ch = blockIdx.x;            // 0..31
  const int b  = blockIdx.y;
  const int s0 = ch * BM;
  const int wid = tid >> 6, l = tid & 63;
  const int wr = wid >> 2;              // 0..1  (64-row half)
  const int wc = wid & 3;               // 0..3  (64-u quarter)
  const int il = l & 15, kg = l >> 4;

  const float* optb = options + ((size_t)b * SS + s0) * DD;

  // ---- precomputed staging geometry ----
  // A: slot s = i*512 + tid; row = s>>3, k8 = s&7
  const int rowA0 = tid >> 3,            k8A0 = tid & 7;
  const int rowA1 = (tid + 512) >> 3,    k8A1 = tid & 7;
  const int awb0 = rowA0 * 128 + ((k8A0 ^ (rowA0 & 7)) << 4);
  const int awb1 = rowA1 * 128 + ((k8A1 ^ (rowA1 & 7)) << 4);
  // B via global_load_lds: call i stages 64 slots at lds base (wid*4+i)*1024
  int uB[4], kB[4];
#pragma unroll
  for (int i = 0; i < 4; ++i) {
    int s = (wid * 4 + i) * 64 + l;
    uB[i] = s >> 3;
    kB[i] = ((s & 7) ^ (uB[i] & 7)) * 8;   // element offset within 64-k chunk
  }
  // ---- MFMA ds_read offsets (constant across kc0) ----
  int aoff[4][2], boff[4][2];
#pragma unroll
  for (int mi = 0; mi < 4; ++mi) {
    int row = wr * 64 + mi * 16 + il;
#pragma unroll
    for (int kc = 0; kc < 2; ++kc)
      aoff[mi][kc] = row * 128 + (((kc * 4 + kg) ^ (row & 7)) << 4);
  }
#pragma unroll
  for (int ni = 0; ni < 4; ++ni) {
    int u = wc * 64 + ni * 16 + il;
#pragma unroll
    for (int kc = 0; kc < 2; ++kc)
      boff[ni][kc] = u * 128 + (((kc * 4 + kg) ^ (u & 7)) << 4);
  }

  f32x4 acc[4][4];
#pragma unroll
  for (int mi = 0; mi < 4; ++mi)
#pragma unroll
    for (int ni = 0; ni < 4; ++ni) {
      f32x4 z = {0.f, 0.f, 0.f, 0.f};
      acc[mi][ni] = z;
    }

  for (int kc0 = 0; kc0 < DD; kc0 += 64) {
    // B stage: async global->LDS, 16B per lane, pre-swizzled source
#pragma unroll
    for (int i = 0; i < 4; ++i) {
      __builtin_amdgcn_global_load_lds(
          (const __attribute__((address_space(1))) void*)(w2t + (size_t)uB[i] * DD + kc0 + kB[i]),
          (__attribute__((address_space(3))) void*)(bB + (wid * 4 + i) * 1024),
          16, 0, 0);
    }
    // A stage: coalesced fp32 loads -> bf16 pack -> swizzled ds_write_b128
    {
      const float* a0 = optb + (size_t)rowA0 * DD + kc0 + k8A0 * 8;
      float4 f0 = *(const float4*)a0;
      float4 f1 = *(const float4*)(a0 + 4);
      *(short8*)(aB + awb0) = bfpack8(f0, f1);
      const float* a1 = optb + (size_t)rowA1 * DD + kc0 + k8A1 * 8;
      float4 g0 = *(const float4*)a1;
      float4 g1 = *(const float4*)(a1 + 4);
      *(short8*)(aB + awb1) = bfpack8(g0, g1);
    }
    __syncthreads();
#pragma unroll
    for (int kc = 0; kc < 2; ++kc) {
      short8 af[4];
#pragma unroll
      for (int mi = 0; mi < 4; ++mi) af[mi] = *(const short8*)(aB + aoff[mi][kc]);
#pragma unroll
      for (int ni = 0; ni < 4; ++ni) {
        short8 bf = *(const short8*)(bB + boff[ni][kc]);
#pragma unroll
        for (int mi = 0; mi < 4; ++mi)
          acc[mi][ni] = __builtin_amdgcn_mfma_f32_16x16x32_bf16(af[mi], bf, acc[mi][ni], 0, 0, 0);
      }
    }
    __syncthreads();
  }

  // ---- epilogue (A/B tiles dead; overlay) ----
  if (tid < 256) { posvL[tid] = posb[b * UU + tid]; vvL[tid] = V[tid]; }
  __syncthreads();

  float part_r[4][4];
#pragma unroll
  for (int mi = 0; mi < 4; ++mi)
#pragma unroll
    for (int r = 0; r < 4; ++r) part_r[mi][r] = 0.f;

#pragma unroll
  for (int ni = 0; ni < 4; ++ni) {
    int u = wc * 64 + ni * 16 + il;
    float pv = posvL[u], vv = vvL[u];
#pragma unroll
    for (int mi = 0; mi < 4; ++mi)
#pragma unroll
      for (int r = 0; r < 4; ++r) {
        float x = acc[mi][ni][r] + pv;
        float t = 1.f - __fdividef(2.f, __expf(2.f * x) + 1.f);
        part_r[mi][r] = fmaf(t, vv, part_r[mi][r]);
      }
  }
#pragma unroll
  for (int mi = 0; mi < 4; ++mi)
#pragma unroll
    for (int r = 0; r < 4; ++r) {
      float p = part_r[mi][r];
      p += __shfl_xor(p, 1);
      p += __shfl_xor(p, 2);
      p += __shfl_xor(p, 4);
      p += __shfl_xor(p, 8);
      part_r[mi][r] = p;
    }
  if (il == 0) {
#pragma unroll
    for (int mi = 0; mi < 4; ++mi)
#pragma unroll
      for (int r = 0; r < 4; ++r)
        red[wr * 64 + mi * 16 + kg * 4 + r][wc] = part_r[mi][r];
  }
  __syncthreads();

  // softmax stats over 128 rows (one wave: 2 rows/lane)
  const float bvv = bvp[0];
  if (tid < 64) {
    float4 r0 = *(const float4*)red[tid];
    float4 r1 = *(const float4*)red[tid + 64];
    float sv0 = r0.x + r0.y + r0.z + r0.w + bvv;
    float sv1 = r1.x + r1.y + r1.z + r1.w + bvv;
    scores[(size_t)b * SS + s0 + tid] = sv0;
    scores[(size_t)b * SS + s0 + tid + 64] = sv1;
    float m = fmaxf(sv0, sv1);
#pragma unroll
    for (int off = 32; off >= 1; off >>= 1) m = fmaxf(m, __shfl_xor(m, off));
    float p0 = __expf(sv0 - m), p1 = __expf(sv1 - m);
    float ls = p0 + p1;
#pragma unroll
    for (int off = 32; off >= 1; off >>= 1) ls += __shfl_xor(ls, off);
    pbuf[tid] = p0;
    pbuf[tid + 64] = p1;
    if (tid == 0) ml[b * NCH + ch] = make_float2(m, ls);
  }
  __syncthreads();

  // partial context: fp32 re-read of the tile (L2/L3-hot)
  {
    int rg = tid >> 6;
    int d4 = (tid & 63) << 2;
    float a0 = 0.f, a1 = 0.f, a2 = 0.f, a3 = 0.f;
#pragma unroll 4
    for (int i = 0; i < 16; ++i) {
      int s = i * 8 + rg;
      const float4 o = *(const float4*)(optb + (size_t)s * DD + d4);
      float w = pbuf[s];
      a0 = fmaf(w, o.x, a0); a1 = fmaf(w, o.y, a1);
      a2 = fmaf(w, o.z, a2); a3 = fmaf(w, o.w, a3);
    }
    pr[tid] = make_float4(a0, a1, a2, a3);
  }
  __syncthreads();
  if (tid < 64) {
    float4 o = pr[tid];
#pragma unroll
    for (int g = 1; g < 8; ++g) {
      float4 v = pr[g * 64 + tid];
      o.x += v.x; o.y += v.y; o.z += v.z; o.w += v.w;
    }
    *(float4*)&part[(((size_t)b * NCH + ch) * DD) + (tid << 2)] = o;
  }
}

// K3: per batch — combine 32 chunk partials, emit context + weights
__global__ __launch_bounds__(256) void k_final(
    const float* __restrict__ scores, const float* __restrict__ part,
    const float2* __restrict__ ml, float* __restrict__ ctx,
    float* __restrict__ wgt) {
  __shared__ float ms[NCH], lsh[NCH];
  int b = blockIdx.x, t = threadIdx.x;
  if (t < NCH) { float2 v = ml[b * NCH + t]; ms[t] = v.x; lsh[t] = v.y; }
  __syncthreads();
  float gm = ms[0];
#pragma unroll
  for (int i = 1; i < NCH; ++i) gm = fmaxf(gm, ms[i]);
  float gs = 0.f;
#pragma unroll
  for (int i = 0; i < NCH; ++i) gs += lsh[i] * __expf(ms[i] - gm);
  float inv = 1.f / gs;
  float acc = 0.f;
#pragma unroll 4
  for (int i = 0; i < NCH; ++i)
    acc += part[((size_t)b * NCH + i) * DD + t] * __expf(ms[i] - gm);
  ctx[b * DD + t] = acc * inv;
  const float* sb = scores + (size_t)b * SS;
  float* wb = wgt + (size_t)b * SS;
#pragma unroll 4
  for (int i = 0; i < 16; ++i) {
    int s = i * 256 + t;
    wb[s] = __expf(sb[s] - gm) * inv;
  }
}

extern "C" void kernel_launch(void* const* d_in, const int* in_sizes, int n_in,
                              void* d_out, int out_size, void* d_ws, size_t ws_size,
                              hipStream_t stream) {
  const float* position = (const float*)d_in[0];
  const float* options  = (const float*)d_in[1];
  const float* W1 = (const float*)d_in[2];
  const float* b1 = (const float*)d_in[3];
  const float* W2 = (const float*)d_in[4];
  const float* b2 = (const float*)d_in[5];
  const float* V  = (const float*)d_in[6];
  const float* bv = (const float*)d_in[7];

  float* out = (float*)d_out;
  float* ctx_out = out;              // [32,256]
  float* wgt_out = out + BB * DD;    // [32,4096]

  char* ws = (char*)d_ws;
  float* posb         = (float*)ws;                          // 32 KB
  unsigned short* w2t = (unsigned short*)(ws + 32 * 1024);   // 128 KB
  float* scores       = (float*)(ws + 160 * 1024);           // 512 KB
  float* part         = (float*)(ws + 672 * 1024);           // 1 MB
  float2* ml          = (float2*)(ws + 672 * 1024 + 1024 * 1024); // 8 KB

  k_posproj<<<BB, 256, 0, stream>>>(position, W1, b1, b2, posb);
  k_w2t<<<dim3(16, 16), 256, 0, stream>>>(W2, w2t);
  k_score_ctx<<<dim3(NCH, BB), 512, 0, stream>>>(options, w2t, posb, V, bv,
                                                 scores, part, ml);
  k_final<<<BB, 256, 0, stream>>>(scores, part, ml, ctx_out, wgt_out);
}